// Round 4
// baseline (63.578 us; speedup 1.0000x reference)
//
#include <hip/hip_runtime.h>
#include <stdint.h>

typedef float  f32x4 __attribute__((ext_vector_type(4)));
typedef short  s16x8 __attribute__((ext_vector_type(8)));

constexpr int Kdim    = 1024;
constexpr int Cdim    = 16;
constexpr int NCHUNK  = 8;                 // grid = 512 -> 2 blocks/CU (LDS 74.2KB x2 <= 160KB)
constexpr int ROWS_CH = 128;               // rows per block
constexpr int TROWS   = 32;                // rows per LDS tile
constexpr int NTILE   = ROWS_CH / TROWS;   // 4
constexpr int RS      = Kdim + 8;          // bf16 row stride (2064B = 129*16B: aligned, rotates banks)

static __device__ __forceinline__ ushort f2bf(float f) {
  uint32_t u = __builtin_bit_cast(uint32_t, f);
  u += 0x7FFFu + ((u >> 16) & 1u);         // RNE
  return (ushort)(u >> 16);
}
static __device__ __forceinline__ float bf2f(ushort u) {
  return __builtin_bit_cast(float, (uint32_t)u << 16);
}

// LDS-only barrier: ds ops drained, global prefetches stay IN FLIGHT across it
// (__syncthreads would emit s_waitcnt vmcnt(0) and kill the cross-tile ring).
static __device__ __forceinline__ void bar_lds() {
  __builtin_amdgcn_sched_barrier(0);
  asm volatile("s_waitcnt lgkmcnt(0)" ::: "memory");
  __builtin_amdgcn_s_barrier();
  __builtin_amdgcn_sched_barrier(0);
}

// K0: prep — W_col -> bf16 [c][j]; W_row -> transposed fp32 [i][c]
__global__ __launch_bounds__(256) void k_prep(const float* __restrict__ Wr, const float* __restrict__ Wc,
                                              ushort* __restrict__ Wcb, float* __restrict__ Wrt) {
  int id = blockIdx.x * 256 + threadIdx.x;   // 0..16383
  int c = id >> 10, i = id & 1023;
  Wcb[id] = f2bf(Wc[id]);
  Wrt[i * Cdim + c] = Wr[id];
}

// K1: one read of x. r-direction on VALU (fp32 regs -> bf16 partials out), col via MFMA -> col_ws [b][c][i].
// 2 blocks/CU; B-operand (Wcb) hoisted to registers; LDS-only barriers keep prefetch in flight.
__global__ __launch_bounds__(256, 2) void k_main(const float* __restrict__ x, const float* __restrict__ Wrt,
                                                 const ushort* __restrict__ Wcb, ushort* __restrict__ r_bf,
                                                 float* __restrict__ col_ws) {
  __shared__ ushort x_l[TROWS * RS];        // 66,048 B bf16 tile
  __shared__ float  colp[2][4 * 64 * 4];    //  8,192 B MFMA partials (double-buffered)

  const int t    = threadIdx.x;
  const int lane = t & 63;
  const int w    = t >> 6;
  const int b    = blockIdx.x >> 3;
  const int ch   = blockIdx.x & 7;
  const int i0   = ch * ROWS_CH;
  const float* xb = x + (size_t)b * Kdim * Kdim;
  const float* xt = xb + 4 * t;

  // ---- hoist B operand: wave w covers K-half (w>>1); addresses are tile-invariant
  const int kh = w >> 1;
  const ushort* brow = Wcb + (size_t)(lane & 15) * Kdim;
  const int kg = lane >> 4;
  s16x8 wfrag[16];
  #pragma unroll
  for (int s = 0; s < 16; ++s)
    wfrag[s] = *(const s16x8*)(brow + (kh * 16 + s) * 32 + kg * 8);

  float racc[Cdim][4];
  #pragma unroll
  for (int c = 0; c < Cdim; ++c) { racc[c][0] = racc[c][1] = racc[c][2] = racc[c][3] = 0.f; }

  auto proc_row = [&](int row, int grow, f32x4 v) {
    const float* wrr = Wrt + (size_t)grow * Cdim;   // 16 uniform floats -> s_load
    #pragma unroll
    for (int c = 0; c < Cdim; ++c) {
      const float wv = wrr[c];
      racc[c][0] = fmaf(wv, v.x, racc[c][0]);
      racc[c][1] = fmaf(wv, v.y, racc[c][1]);
      racc[c][2] = fmaf(wv, v.z, racc[c][2]);
      racc[c][3] = fmaf(wv, v.w, racc[c][3]);
    }
    ushort4 u4 = make_ushort4(f2bf(v.x), f2bf(v.y), f2bf(v.z), f2bf(v.w));
    *(ushort4*)&x_l[row * RS + 4 * t] = u4;
  };

  auto phase_c = [&](int p, int r0p) {      // combine K-halves, store col in [b][c][i] (contig f32x4 in i)
    if (t < 128) {
      const int it = t >> 6;
      const int l  = t & 63;
      f32x4 va = *(const f32x4*)&colp[p][(it * 64 + l) * 4];
      f32x4 vb = *(const f32x4*)&colp[p][((it + 2) * 64 + l) * 4];
      const int c     = l & 15;
      const int rbase = r0p + it * 16 + ((l >> 4) << 2);   // D row = (lane>>4)*4 + q
      f32x4 o = va + vb;
      *(f32x4*)(col_ws + ((size_t)(b * Cdim + c)) * Kdim + rbase) = o;
    }
  };

  // depth-8 register prefetch ring: 128 B/thread in flight -> 64 KB/CU at 2 blocks
  f32x4 pa0, pa1, pa2, pa3, pb0, pb1, pb2, pb3;
  pa0 = *(const f32x4*)(xt + (size_t)(i0 + 0) * Kdim);
  pa1 = *(const f32x4*)(xt + (size_t)(i0 + 1) * Kdim);
  pa2 = *(const f32x4*)(xt + (size_t)(i0 + 2) * Kdim);
  pa3 = *(const f32x4*)(xt + (size_t)(i0 + 3) * Kdim);

  for (int tl = 0; tl < NTILE; ++tl) {
    const int r0 = i0 + tl * TROWS;

    if (tl) phase_c((tl - 1) & 1, r0 - TROWS);   // prev tile's col store overlaps phase A

    // ---- phase A: stream 32 rows; pa/pb alternate; last prefetch targets next tile (survives barriers)
    for (int g = 0; g < 8; g += 2) {
      const int nr1 = r0 + (g + 1) * 4;
      pb0 = *(const f32x4*)(xt + (size_t)(nr1 + 0) * Kdim);
      pb1 = *(const f32x4*)(xt + (size_t)(nr1 + 1) * Kdim);
      pb2 = *(const f32x4*)(xt + (size_t)(nr1 + 2) * Kdim);
      pb3 = *(const f32x4*)(xt + (size_t)(nr1 + 3) * Kdim);
      proc_row(g * 4 + 0, r0 + g * 4 + 0, pa0);
      proc_row(g * 4 + 1, r0 + g * 4 + 1, pa1);
      proc_row(g * 4 + 2, r0 + g * 4 + 2, pa2);
      proc_row(g * 4 + 3, r0 + g * 4 + 3, pa3);
      const int nr2 = r0 + (g + 2) * 4;          // == r0+32 when g==6 -> next tile group 0
      if (g + 2 < 8 || tl + 1 < NTILE) {         // guards OOB read past chunk end
        pa0 = *(const f32x4*)(xt + (size_t)(nr2 + 0) * Kdim);
        pa1 = *(const f32x4*)(xt + (size_t)(nr2 + 1) * Kdim);
        pa2 = *(const f32x4*)(xt + (size_t)(nr2 + 2) * Kdim);
        pa3 = *(const f32x4*)(xt + (size_t)(nr2 + 3) * Kdim);
      }
      proc_row(g * 4 + 4, nr1 + 0, pb0);
      proc_row(g * 4 + 5, nr1 + 1, pb1);
      proc_row(g * 4 + 6, nr1 + 2, pb2);
      proc_row(g * 4 + 7, nr1 + 3, pb3);
    }
    bar_lds();                                   // x_l visible; global ring stays in flight

    // ---- phase B: col-direction MFMA. wave w: i-tile (w&1), K-half (w>>1). B operand from regs.
    {
      const int it   = w & 1;
      const int arow = it * 16 + (lane & 15);
      f32x4 acc = {0.f, 0.f, 0.f, 0.f};
      #pragma unroll
      for (int s = 0; s < 16; ++s) {
        const int ks = kh * 16 + s;
        s16x8 a = *(const s16x8*)&x_l[arow * RS + ks * 32 + kg * 8];
        acc = __builtin_amdgcn_mfma_f32_16x16x32_bf16(a, wfrag[s], acc, 0, 0, 0);
      }
      *(f32x4*)&colp[tl & 1][(w * 64 + lane) * 4] = acc;
    }
    bar_lds();                                   // x_l free for next phase A; colp visible
  }
  phase_c((NTILE - 1) & 1, i0 + (NTILE - 1) * TROWS);

  // ---- write r partials for this chunk as bf16: [b][ch][c][k], coalesced 8B stores
  ushort* rp = r_bf + ((size_t)(b * NCHUNK + ch) * Cdim) * Kdim + 4 * t;
  #pragma unroll
  for (int c = 0; c < Cdim; ++c) {
    ushort4 u4 = make_ushort4(f2bf(racc[c][0]), f2bf(racc[c][1]), f2bf(racc[c][2]), f2bf(racc[c][3]));
    *(ushort4*)(rp + (size_t)c * Kdim) = u4;
  }
}

// K2 (fused): per (b,c): r = sum of bf16 chunk partials; s = dot(r+br, col+bc); broadcast-write 1024 outputs
__global__ __launch_bounds__(256) void k_out(const ushort* __restrict__ r_bf, const float* __restrict__ col_ws,
                                             const float* __restrict__ b_row, const float* __restrict__ b_col,
                                             float* __restrict__ out) {
  const int bid = blockIdx.x;             // 0..1023
  const int b = bid >> 4, c = bid & 15;
  const int t = threadIdx.x;
  const float br = b_row[c], bc = b_col[c];

  f32x4 rv = {0.f, 0.f, 0.f, 0.f};
  #pragma unroll
  for (int ch = 0; ch < NCHUNK; ++ch) {
    ushort4 u = *(const ushort4*)(r_bf + ((size_t)(b * NCHUNK + ch) * Cdim + c) * Kdim + 4 * t);
    rv.x += bf2f(u.x); rv.y += bf2f(u.y); rv.z += bf2f(u.z); rv.w += bf2f(u.w);
  }
  f32x4 cv = *(const f32x4*)(col_ws + ((size_t)(b * Cdim + c)) * Kdim + 4 * t);
  float part = 0.f;
  #pragma unroll
  for (int q = 0; q < 4; ++q) part += (rv[q] + br) * (cv[q] + bc);

  #pragma unroll
  for (int off = 1; off < 64; off <<= 1) part += __shfl_xor(part, off);
  __shared__ float wsum[4];
  if ((t & 63) == 0) wsum[t >> 6] = part;
  __syncthreads();
  const float s = wsum[0] + wsum[1] + wsum[2] + wsum[3];

  f32x4 o = {s, s, s, s};
  *(f32x4*)(out + ((size_t)(b * Cdim + c)) * Kdim + 4 * t) = o;
}

extern "C" void kernel_launch(void* const* d_in, const int* in_sizes, int n_in,
                              void* d_out, int out_size, void* d_ws, size_t ws_size,
                              hipStream_t stream) {
  const float* x  = (const float*)d_in[0];
  const float* Wr = (const float*)d_in[1];
  const float* br = (const float*)d_in[2];
  const float* Wc = (const float*)d_in[3];
  const float* bc = (const float*)d_in[4];
  float* out = (float*)d_out;

  char* ws = (char*)d_ws;
  ushort* r_bf   = (ushort*)ws;                                  // 64*8*16*1024*2 = 16,777,216 B
  float*  col_ws = (float*)(ws + 16777216);                      // 64*16*1024*4   =  4,194,304 B
  ushort* wcb    = (ushort*)(ws + 16777216 + 4194304);           // 16*1024*2      =     32,768 B
  float*  wrt    = (float*)(ws + 16777216 + 4194304 + 32768);    // 1024*16*4      =     65,536 B

  k_prep<<<64, 256, 0, stream>>>(Wr, Wc, wcb, wrt);
  k_main<<<512, 256, 0, stream>>>(x, wrt, wcb, r_bf, col_ws);
  k_out<<<1024, 256, 0, stream>>>(r_bf, col_ws, br, bc, out);
}

// Round 5
// 60.475 us; speedup vs baseline: 1.0513x; 1.0513x over previous
//
#include <hip/hip_runtime.h>
#include <stdint.h>

typedef float  f32x4 __attribute__((ext_vector_type(4)));
typedef short  s16x8 __attribute__((ext_vector_type(8)));

constexpr int Kdim    = 1024;
constexpr int Cdim    = 16;
constexpr int NCHUNK  = 8;                 // grid = 512 -> 2 blocks/CU (LDS 74.2KB x2 <= 160KB)
constexpr int ROWS_CH = 128;               // rows per block
constexpr int TROWS   = 32;                // rows per LDS tile
constexpr int NTILE   = ROWS_CH / TROWS;   // 4
constexpr int RS      = Kdim + 8;          // bf16 row stride (2064B = 129*16B: aligned, rotates banks)

static __device__ __forceinline__ ushort f2bf(float f) {
  uint32_t u = __builtin_bit_cast(uint32_t, f);
  u += 0x7FFFu + ((u >> 16) & 1u);         // RNE
  return (ushort)(u >> 16);
}
static __device__ __forceinline__ float bf2f(ushort u) {
  return __builtin_bit_cast(float, (uint32_t)u << 16);
}

// LDS-only barrier: ds ops drained, global prefetches stay IN FLIGHT across it.
static __device__ __forceinline__ void bar_lds() {
  __builtin_amdgcn_sched_barrier(0);
  asm volatile("s_waitcnt lgkmcnt(0)" ::: "memory");
  __builtin_amdgcn_s_barrier();
  __builtin_amdgcn_sched_barrier(0);
}

// K1: one read of x. r-direction on VALU (fp32 regs -> bf16 partials), col via MFMA -> col_ws [b][c][i].
// W_col converted to bf16 fragments in-register (L2-hot fp32 reads); W_row read via uniform s_loads.
__global__ __launch_bounds__(256, 2) void k_main(const float* __restrict__ x, const float* __restrict__ Wr,
                                                 const float* __restrict__ Wc, ushort* __restrict__ r_bf,
                                                 float* __restrict__ col_ws) {
  __shared__ ushort x_l[TROWS * RS];        // 66,048 B bf16 tile
  __shared__ float  colp[2][4 * 64 * 4];    //  8,192 B MFMA partials (double-buffered)

  const int t    = threadIdx.x;
  const int lane = t & 63;
  const int w    = t >> 6;
  const int b    = blockIdx.x >> 3;
  const int ch   = blockIdx.x & 7;
  const int i0   = ch * ROWS_CH;
  const float* xb = x + (size_t)b * Kdim * Kdim;
  const float* xt = xb + 4 * t;

  // ---- start the x prefetch ring FIRST (HBM latency long); depth-8: 128B/thread in flight
  f32x4 pa0, pa1, pa2, pa3, pb0, pb1, pb2, pb3;
  pa0 = *(const f32x4*)(xt + (size_t)(i0 + 0) * Kdim);
  pa1 = *(const f32x4*)(xt + (size_t)(i0 + 1) * Kdim);
  pa2 = *(const f32x4*)(xt + (size_t)(i0 + 2) * Kdim);
  pa3 = *(const f32x4*)(xt + (size_t)(i0 + 3) * Kdim);

  // ---- hoist B operand: wave w covers K-half (w>>1); build bf16 fragments from fp32 Wc (L2-hot)
  const int kh = w >> 1;
  const int kg = lane >> 4;
  const float* wcrow = Wc + (size_t)(lane & 15) * Kdim;
  s16x8 wfrag[16];
  #pragma unroll
  for (int s = 0; s < 16; ++s) {
    const float* p = wcrow + (kh * 16 + s) * 32 + kg * 8;
    f32x4 lo = *(const f32x4*)p;
    f32x4 hi = *(const f32x4*)(p + 4);
    s16x8 f;
    f[0] = (short)f2bf(lo.x); f[1] = (short)f2bf(lo.y); f[2] = (short)f2bf(lo.z); f[3] = (short)f2bf(lo.w);
    f[4] = (short)f2bf(hi.x); f[5] = (short)f2bf(hi.y); f[6] = (short)f2bf(hi.z); f[7] = (short)f2bf(hi.w);
    wfrag[s] = f;
  }

  float racc[Cdim][4];
  #pragma unroll
  for (int c = 0; c < Cdim; ++c) { racc[c][0] = racc[c][1] = racc[c][2] = racc[c][3] = 0.f; }

  auto proc_row = [&](int row, int grow, f32x4 v) {
    const float* wrp = Wr + grow;            // Wr[c][grow]: uniform -> s_load, scalar-cache resident
    #pragma unroll
    for (int c = 0; c < Cdim; ++c) {
      const float wv = wrp[(size_t)c * Kdim];
      racc[c][0] = fmaf(wv, v.x, racc[c][0]);
      racc[c][1] = fmaf(wv, v.y, racc[c][1]);
      racc[c][2] = fmaf(wv, v.z, racc[c][2]);
      racc[c][3] = fmaf(wv, v.w, racc[c][3]);
    }
    ushort4 u4 = make_ushort4(f2bf(v.x), f2bf(v.y), f2bf(v.z), f2bf(v.w));
    *(ushort4*)&x_l[row * RS + 4 * t] = u4;
  };

  auto phase_c = [&](int p, int r0p) {      // combine K-halves, store col in [b][c][i] (contig in i)
    if (t < 128) {
      const int it = t >> 6;
      const int l  = t & 63;
      f32x4 va = *(const f32x4*)&colp[p][(it * 64 + l) * 4];
      f32x4 vb = *(const f32x4*)&colp[p][((it + 2) * 64 + l) * 4];
      const int c     = l & 15;
      const int rbase = r0p + it * 16 + ((l >> 4) << 2);   // D row = (lane>>4)*4 + q
      f32x4 o = va + vb;
      *(f32x4*)(col_ws + ((size_t)(b * Cdim + c)) * Kdim + rbase) = o;
    }
  };

  for (int tl = 0; tl < NTILE; ++tl) {
    const int r0 = i0 + tl * TROWS;

    if (tl) phase_c((tl - 1) & 1, r0 - TROWS);   // prev tile's col store overlaps phase A

    // ---- phase A: stream 32 rows; pa/pb alternate; last prefetch targets next tile (survives barriers)
    for (int g = 0; g < 8; g += 2) {
      const int nr1 = r0 + (g + 1) * 4;
      pb0 = *(const f32x4*)(xt + (size_t)(nr1 + 0) * Kdim);
      pb1 = *(const f32x4*)(xt + (size_t)(nr1 + 1) * Kdim);
      pb2 = *(const f32x4*)(xt + (size_t)(nr1 + 2) * Kdim);
      pb3 = *(const f32x4*)(xt + (size_t)(nr1 + 3) * Kdim);
      proc_row(g * 4 + 0, r0 + g * 4 + 0, pa0);
      proc_row(g * 4 + 1, r0 + g * 4 + 1, pa1);
      proc_row(g * 4 + 2, r0 + g * 4 + 2, pa2);
      proc_row(g * 4 + 3, r0 + g * 4 + 3, pa3);
      const int nr2 = r0 + (g + 2) * 4;          // == r0+32 when g==6 -> next tile group 0
      if (g + 2 < 8 || tl + 1 < NTILE) {         // guards OOB read past chunk end
        pa0 = *(const f32x4*)(xt + (size_t)(nr2 + 0) * Kdim);
        pa1 = *(const f32x4*)(xt + (size_t)(nr2 + 1) * Kdim);
        pa2 = *(const f32x4*)(xt + (size_t)(nr2 + 2) * Kdim);
        pa3 = *(const f32x4*)(xt + (size_t)(nr2 + 3) * Kdim);
      }
      proc_row(g * 4 + 4, nr1 + 0, pb0);
      proc_row(g * 4 + 5, nr1 + 1, pb1);
      proc_row(g * 4 + 6, nr1 + 2, pb2);
      proc_row(g * 4 + 7, nr1 + 3, pb3);
    }
    bar_lds();                                   // x_l visible; global ring stays in flight

    // ---- phase B: col-direction MFMA. wave w: i-tile (w&1), K-half (w>>1). B operand from regs.
    {
      const int it   = w & 1;
      const int arow = it * 16 + (lane & 15);
      f32x4 acc = {0.f, 0.f, 0.f, 0.f};
      #pragma unroll
      for (int s = 0; s < 16; ++s) {
        const int ks = kh * 16 + s;
        s16x8 a = *(const s16x8*)&x_l[arow * RS + ks * 32 + kg * 8];
        acc = __builtin_amdgcn_mfma_f32_16x16x32_bf16(a, wfrag[s], acc, 0, 0, 0);
      }
      *(f32x4*)&colp[tl & 1][(w * 64 + lane) * 4] = acc;
    }
    bar_lds();                                   // x_l free for next phase A; colp visible
  }
  phase_c((NTILE - 1) & 1, i0 + (NTILE - 1) * TROWS);

  // ---- write r partials for this chunk as bf16: [b][ch][c][k], coalesced 8B stores
  ushort* rp = r_bf + ((size_t)(b * NCHUNK + ch) * Cdim) * Kdim + 4 * t;
  #pragma unroll
  for (int c = 0; c < Cdim; ++c) {
    ushort4 u4 = make_ushort4(f2bf(racc[c][0]), f2bf(racc[c][1]), f2bf(racc[c][2]), f2bf(racc[c][3]));
    *(ushort4*)(rp + (size_t)c * Kdim) = u4;
  }
}

// K2 (fused): per (b,c): r = sum of bf16 chunk partials; s = dot(r+br, col+bc); broadcast-write 1024 outputs
__global__ __launch_bounds__(256) void k_out(const ushort* __restrict__ r_bf, const float* __restrict__ col_ws,
                                             const float* __restrict__ b_row, const float* __restrict__ b_col,
                                             float* __restrict__ out) {
  const int bid = blockIdx.x;             // 0..1023
  const int b = bid >> 4, c = bid & 15;
  const int t = threadIdx.x;
  const float br = b_row[c], bc = b_col[c];

  f32x4 rv = {0.f, 0.f, 0.f, 0.f};
  #pragma unroll
  for (int ch = 0; ch < NCHUNK; ++ch) {
    ushort4 u = *(const ushort4*)(r_bf + ((size_t)(b * NCHUNK + ch) * Cdim + c) * Kdim + 4 * t);
    rv.x += bf2f(u.x); rv.y += bf2f(u.y); rv.z += bf2f(u.z); rv.w += bf2f(u.w);
  }
  f32x4 cv = *(const f32x4*)(col_ws + ((size_t)(b * Cdim + c)) * Kdim + 4 * t);
  float part = 0.f;
  #pragma unroll
  for (int q = 0; q < 4; ++q) part += (rv[q] + br) * (cv[q] + bc);

  #pragma unroll
  for (int off = 1; off < 64; off <<= 1) part += __shfl_xor(part, off);
  __shared__ float wsum[4];
  if ((t & 63) == 0) wsum[t >> 6] = part;
  __syncthreads();
  const float s = wsum[0] + wsum[1] + wsum[2] + wsum[3];

  f32x4 o = {s, s, s, s};
  *(f32x4*)(out + ((size_t)(b * Cdim + c)) * Kdim + 4 * t) = o;
}

extern "C" void kernel_launch(void* const* d_in, const int* in_sizes, int n_in,
                              void* d_out, int out_size, void* d_ws, size_t ws_size,
                              hipStream_t stream) {
  const float* x  = (const float*)d_in[0];
  const float* Wr = (const float*)d_in[1];
  const float* br = (const float*)d_in[2];
  const float* Wc = (const float*)d_in[3];
  const float* bc = (const float*)d_in[4];
  float* out = (float*)d_out;

  char* ws = (char*)d_ws;
  ushort* r_bf   = (ushort*)ws;                                  // 64*8*16*1024*2 = 16,777,216 B
  float*  col_ws = (float*)(ws + 16777216);                      // 64*16*1024*4   =  4,194,304 B

  k_main<<<512, 256, 0, stream>>>(x, Wr, Wc, r_bf, col_ws);
  k_out<<<1024, 256, 0, stream>>>(r_bf, col_ws, br, bc, out);
}